// Round 7
// baseline (1209.777 us; speedup 1.0000x reference)
//
#include <hip/hip_runtime.h>

typedef unsigned short u16;
typedef __attribute__((ext_vector_type(8))) short short8;
typedef __attribute__((ext_vector_type(4))) short short4_t;
typedef __attribute__((ext_vector_type(4))) float f32x4;

#define NLAYER 6
#define NH 16
#define DMODEL 1024
#define DHEAD 64
#define NVOCAB 32000
#define NB 2
#define NS 1024
#define NDFF 4096
#define MTOK (NB*NS)   // 2048

__device__ __forceinline__ u16 f2b(float f) {
    union { float f; unsigned u; } x; x.f = f;
    unsigned r = x.u + 0x7fffu + ((x.u >> 16) & 1u);
    return (u16)(r >> 16);
}

#define GLL16(gp, lp) __builtin_amdgcn_global_load_lds( \
    (const __attribute__((address_space(1))) void*)(gp), \
    (__attribute__((address_space(3))) void*)(lp), 16, 0, 0)

// ---------------------------------------------------------------------------
// Vectorized 64x64 transpose + f32->bf16: src [z][R][C] f32 -> dst [z][C][R] bf16
__global__ __launch_bounds__(256) void trans64(
    const float* __restrict__ src, u16* __restrict__ dst,
    int R, int C, long sStride, long dStride)
{
    __shared__ float sh[64][65];
    const int c0 = blockIdx.x * 64, r0 = blockIdx.y * 64;
    const float* s = src + (long)blockIdx.z * sStride;
    u16* d = dst + (long)blockIdx.z * dStride;
    const int tid = threadIdx.x;
    const int lr = tid >> 4, lc = (tid & 15) * 4;
    #pragma unroll
    for (int q = 0; q < 4; ++q) {
        const float4 v = *(const float4*)(s + (long)(r0 + q * 16 + lr) * C + c0 + lc);
        sh[q * 16 + lr][lc + 0] = v.x;
        sh[q * 16 + lr][lc + 1] = v.y;
        sh[q * 16 + lr][lc + 2] = v.z;
        sh[q * 16 + lr][lc + 3] = v.w;
    }
    __syncthreads();
    #pragma unroll
    for (int k = 0; k < 2; ++k) {
        const int t = tid + 256 * k;
        const int col = t >> 3, rch = (t & 7) * 8;
        u16 tmp[8];
        #pragma unroll
        for (int j = 0; j < 8; ++j) tmp[j] = f2b(sh[rch + j][col]);
        *(short8*)(d + (long)(c0 + col) * R + r0 + rch) = *(const short8*)tmp;
    }
}

// Wq/Wk/Wv: src [NL,H,1024,64] -> dst [NL,3072,1024]
__global__ void transpose_qkv(const float* __restrict__ src, u16* __restrict__ dst, int sel)
{
    __shared__ float t[32][33];
    const int bi = blockIdx.z, l = bi >> 4, h = bi & 15;
    const float* s = src + (long)bi * (DMODEL * DHEAD);
    u16* d = dst + (long)l * 3072 * DMODEL + (long)(sel * 1024 + h * 64) * DMODEL;
    const int c0 = blockIdx.x * 32, r0 = blockIdx.y * 32;
    const int tx = threadIdx.x, ty = threadIdx.y;
    #pragma unroll
    for (int j = 0; j < 32; j += 8)
        t[ty + j][tx] = s[(long)(r0 + ty + j) * DHEAD + c0 + tx];
    __syncthreads();
    #pragma unroll
    for (int j = 0; j < 32; j += 8)
        d[(long)(c0 + ty + j) * DMODEL + r0 + tx] = f2b(t[tx][ty + j]);
}

// ---------------------------------------------------------------------------
__global__ void embed_pe(const int* __restrict__ toks, const float* __restrict__ emb,
                         float* __restrict__ x, u16* __restrict__ xb)
{
    const int row = blockIdx.x;
    const int s = row & (NS - 1);
    const long erow = (long)toks[row] * DMODEL;
    const long base = (long)row * DMODEL;
    #pragma unroll
    for (int j = 0; j < 4; ++j) {
        int d = threadIdx.x + j * 256;
        float ang = (float)s * exp2f(-(float)d * (9.965784284662087f / 1024.f));
        float pe = (d & 1) ? cosf(ang) : sinf(ang);
        float v = emb[erow + d] + pe;
        x[base + d] = v;
        xb[base + d] = f2b(v);
    }
}

// ---------------------------------------------------------------------------
// Residual add + LayerNorm (ND delta buffers, stride pstride), f32x4 vectorized
template<int ND>
__global__ __launch_bounds__(256) void ln_residual(
    const float* __restrict__ xin, const float* __restrict__ delta, size_t pstride,
    const float* __restrict__ g, const float* __restrict__ bb,
    float* __restrict__ xout, u16* __restrict__ xbout)
{
    __shared__ float red[8];
    const long base = (long)blockIdx.x * DMODEL;
    const int d = threadIdx.x * 4;
    f32x4 v = *(const f32x4*)(xin + base + d);
    #pragma unroll
    for (int y = 0; y < ND; ++y)
        v += *(const f32x4*)(delta + base + (size_t)y * pstride + d);
    float sum = v[0] + v[1] + v[2] + v[3];
    float sq  = v[0]*v[0] + v[1]*v[1] + v[2]*v[2] + v[3]*v[3];
    #pragma unroll
    for (int off = 1; off < 64; off <<= 1) {
        sum += __shfl_xor(sum, off, 64);
        sq  += __shfl_xor(sq,  off, 64);
    }
    const int wv = threadIdx.x >> 6, lane = threadIdx.x & 63;
    if (lane == 0) { red[wv] = sum; red[4 + wv] = sq; }
    __syncthreads();
    float ts = red[0] + red[1] + red[2] + red[3];
    float tq = red[4] + red[5] + red[6] + red[7];
    float mu = ts * (1.f / DMODEL);
    float var = tq * (1.f / DMODEL) - mu * mu;
    float rstd = rsqrtf(var + 1e-5f);
    const f32x4 gg = *(const f32x4*)(g + d);
    const f32x4 bv = *(const f32x4*)(bb + d);
    f32x4 yv = (v - mu) * rstd * gg + bv;
    *(f32x4*)(xout + base + d) = yv;
    u16 fourv[4];
    #pragma unroll
    for (int i = 0; i < 4; ++i) fourv[i] = f2b(yv[i]);
    *(short4_t*)(xbout + base + d) = *(const short4_t*)fourv;
}

// ---------------------------------------------------------------------------
// Pipelined GEMM (r5-proven, 16x16x32): C[M,N] = A[M,K] @ Bt[N,K]^T.
// BK=32, 4 LDS buffers, counted vmcnt(8), XOR-swizzled LDS, XCD swizzle.
// EPI: 0=f32 partial (+blockIdx.y*zstride), 1=bf16, 2=relu->bf16, 3=f32+bias
template<int BM, int EPI>
__global__ __launch_bounds__(BM*2, 2) void gemm_pipe(
    const u16* __restrict__ A, const u16* __restrict__ Bt,
    void* __restrict__ Cout, const float* __restrict__ bias,
    int M, int N, int K, int lda, int ldb, size_t zstride)
{
    constexpr int WAVES = BM / 32;
    constexpr int WC = WAVES / 2;
    constexpr int MR = BM / 32;
    constexpr int TILE = BM * 32;

    __shared__ __align__(16) u16 As[4][TILE];
    __shared__ __align__(16) u16 Bs[4][TILE];

    const int nmb = M / BM;
    const int id = blockIdx.x, nwg = gridDim.x;
    const int q = nwg >> 3, r = nwg & 7, xcd = id & 7, loc = id >> 3;
    const int swz = (xcd < r ? xcd * (q + 1) : r * (q + 1) + (xcd - r) * q) + loc;
    const int m0 = (swz % nmb) * BM, n0 = (swz / nmb) * BM;
    const int koff = blockIdx.y * K;

    const int tid = threadIdx.x, wv = tid >> 6, lane = tid & 63;
    const int wr = wv / WC, wc = wv % WC;
    const int lrow = lane & 15, ks = lane >> 4;

    const u16* gsrc[4];
    int ldso[2];
    {
        const int l4 = lane >> 2, s = lane & 3;
        #pragma unroll
        for (int j = 0; j < 2; ++j) {
            const int row = j * (WAVES * 16) + wv * 16 + l4;
            const int x = (row >> 1) & 3;
            gsrc[j]     = A  + (size_t)(m0 + row) * lda + koff + (size_t)((s ^ x) * 8);
            gsrc[2 + j] = Bt + (size_t)(n0 + row) * ldb + koff + (size_t)((s ^ x) * 8);
            ldso[j] = (j * (WAVES * 16) + wv * 16) * 32;
        }
    }
    int aoff[MR], boff[4];
    #pragma unroll
    for (int m = 0; m < MR; ++m) {
        const int row = wr * (BM / 2) + m * 16 + lrow;
        aoff[m] = row * 32 + ((ks ^ ((row >> 1) & 3)) * 8);
    }
    #pragma unroll
    for (int n = 0; n < 4; ++n) {
        const int row = wc * 64 + n * 16 + lrow;
        boff[n] = row * 32 + ((ks ^ ((row >> 1) & 3)) * 8);
    }

    const int NT = K / 32;
    auto ISSUE = [&](int t) {
        const int b = t & 3;
        const size_t ko = (size_t)t * 32;
        #pragma unroll
        for (int j = 0; j < 2; ++j) {
            GLL16(gsrc[j] + ko,     &As[b][ldso[j]]);
            GLL16(gsrc[2 + j] + ko, &Bs[b][ldso[j]]);
        }
    };

    f32x4 acc[MR][4] = {};
    ISSUE(0); ISSUE(1); ISSUE(2);

    for (int t = 0; t < NT; ++t) {
        if (t < NT - 2)       { asm volatile("s_waitcnt vmcnt(8)" ::: "memory"); }
        else if (t == NT - 2) { asm volatile("s_waitcnt vmcnt(4)" ::: "memory"); }
        else                  { asm volatile("s_waitcnt vmcnt(0)" ::: "memory"); }
        __builtin_amdgcn_sched_barrier(0);
        __builtin_amdgcn_s_barrier();
        __builtin_amdgcn_sched_barrier(0);

        const int b = t & 3;
        short8 af[MR], bf[4];
        #pragma unroll
        for (int m = 0; m < MR; ++m) af[m] = *(const short8*)(&As[b][aoff[m]]);
        #pragma unroll
        for (int n = 0; n < 4; ++n)  bf[n] = *(const short8*)(&Bs[b][boff[n]]);
        if (t + 3 < NT) ISSUE(t + 3);
        __builtin_amdgcn_s_setprio(1);
        #pragma unroll
        for (int m = 0; m < MR; ++m)
            #pragma unroll
            for (int n = 0; n < 4; ++n)
                acc[m][n] = __builtin_amdgcn_mfma_f32_16x16x32_bf16(af[m], bf[n], acc[m][n], 0, 0, 0);
        __builtin_amdgcn_s_setprio(0);
    }

    if (EPI == 0 || EPI == 3) {
        __syncthreads();
        float* patch = (float*)((WAVES == 8 && (wv & 4)) ? (void*)&Bs[0][0] : (void*)&As[0][0])
                       + (wv & 3) * (16 * 68);
        const int cc0 = n0 + wc * 64;
        f32x4 bvv = {};
        if (EPI == 3) bvv = *(const f32x4*)(bias + cc0 + (lane & 15) * 4);
        float* C = (float*)Cout + (EPI == 0 ? (size_t)blockIdx.y * zstride : (size_t)0);
        #pragma unroll
        for (int m = 0; m < MR; ++m) {
            #pragma unroll
            for (int n = 0; n < 4; ++n)
                #pragma unroll
                for (int i = 0; i < 4; ++i)
                    patch[(ks * 4 + i) * 68 + n * 16 + lrow] = acc[m][n][i];
            #pragma unroll
            for (int i2 = 0; i2 < 4; ++i2) {
                const int prow = i2 * 4 + ks;
                f32x4 v = *(const f32x4*)(patch + prow * 68 + (lane & 15) * 4);
                if (EPI == 3) v += bvv;
                const int rr = m0 + wr * (BM / 2) + m * 16 + prow;
                *(f32x4*)(C + (size_t)rr * N + cc0 + (lane & 15) * 4) = v;
            }
        }
    } else {
        u16* C = (u16*)Cout;
        #pragma unroll
        for (int m = 0; m < MR; ++m) {
            const int rr = m0 + wr * (BM / 2) + m * 16 + ks * 4;
            #pragma unroll
            for (int n = 0; n < 4; ++n) {
                const int cc = n0 + wc * 64 + n * 16 + lrow;
                #pragma unroll
                for (int i = 0; i < 4; ++i) {
                    float vv = acc[m][n][i];
                    if (EPI == 2) vv = fmaxf(vv, 0.f);
                    C[(size_t)(rr + i) * N + cc] = f2b(vv);
                }
            }
        }
    }
}

// ---------------------------------------------------------------------------
// 8-phase 256x256 GEMM (m201 template port): BK=64, 8 waves, 2 LDS slots,
// 4 phases/K-tile {ds_read || stage 1 half-tile -> barrier -> lgkm0 -> 16 MFMA
// -> barrier}, counted vmcnt(2) once per K-tile. f32 + bias epilogue.
__global__ __launch_bounds__(512, 2) void gemm8p(
    const u16* __restrict__ A, const u16* __restrict__ Bt,
    float* __restrict__ C, const float* __restrict__ bias,
    int M, int N, int K)
{
    __shared__ __align__(16) u16 As[2][2][128 * 64];
    __shared__ __align__(16) u16 Bs[2][2][128 * 64];

    const int nmb = M >> 8;
    const int id = blockIdx.x, nwg = gridDim.x;
    const int q = nwg >> 3, r = nwg & 7, xcd = id & 7, loc = id >> 3;
    const int swz = (xcd < r ? xcd * (q + 1) : r * (q + 1) + (xcd - r) * q) + loc;
    const int m0 = (swz % nmb) * 256, n0 = (swz / nmb) * 256;

    const int tid = threadIdx.x, wv = tid >> 6, lane = tid & 63;
    const int wr = wv >> 2, wc = wv & 3, bh = wc >> 1;
    const int lrow = lane & 15, ks4 = lane >> 4;

    // staging sources: thread covers chunks c = tid, tid+512; row=c>>3, phys unit p=c&7
    const u16* sA[2][2]; const u16* sB[2][2]; int dso[2];
    #pragma unroll
    for (int i = 0; i < 2; ++i) {
        const int c = tid + i * 512, row = c >> 3, pp = c & 7;
        const int uc = (pp ^ (row & 7)) * 8;
        #pragma unroll
        for (int h = 0; h < 2; ++h) {
            sA[i][h] = A  + (size_t)(m0 + h * 128 + row) * K + uc;
            sB[i][h] = Bt + (size_t)(n0 + h * 128 + row) * K + uc;
        }
        dso[i] = c * 8;
    }
    // fragment LDS offsets within a half [128][64], unit ^= row&7
    int aoff[8][2], boff[4][2];
    #pragma unroll
    for (int m = 0; m < 8; ++m) {
        const int hr = m * 16 + lrow;
        #pragma unroll
        for (int kk = 0; kk < 2; ++kk)
            aoff[m][kk] = hr * 64 + (((kk * 4 + ks4) ^ (hr & 7)) * 8);
    }
    #pragma unroll
    for (int n = 0; n < 4; ++n) {
        const int hr = (wc & 1) * 64 + n * 16 + lrow;
        #pragma unroll
        for (int kk = 0; kk < 2; ++kk)
            boff[n][kk] = hr * 64 + (((kk * 4 + ks4) ^ (hr & 7)) * 8);
    }

    auto SA_ = [&](int t, int h) {
        const int s = t & 1; const size_t ko = (size_t)t * 64;
        #pragma unroll
        for (int i = 0; i < 2; ++i) GLL16(sA[i][h] + ko, &As[s][h][dso[i]]);
    };
    auto SB_ = [&](int t, int h) {
        const int s = t & 1; const size_t ko = (size_t)t * 64;
        #pragma unroll
        for (int i = 0; i < 2; ++i) GLL16(sB[i][h] + ko, &Bs[s][h][dso[i]]);
    };

    const int NT = K >> 6;
    // prologue: K-tile 0 fully (B0,B1,A0,A1) then B0 of K-tile 1 -> 10 loads
    SB_(0, 0); SB_(0, 1); SA_(0, 0); SA_(0, 1); SB_(1, 0);

    f32x4 acc[8][4] = {};
    short8 af[4], bf[4];

    for (int t = 0; t < NT; ++t) {
        const int s = t & 1;
        // K-tile boundary: wait staged-ahead loads (counted), then align waves
        if (t < NT - 1) { asm volatile("s_waitcnt vmcnt(2)" ::: "memory"); }
        else            { asm volatile("s_waitcnt vmcnt(0)" ::: "memory"); }
        __builtin_amdgcn_sched_barrier(0);
        __builtin_amdgcn_s_barrier();
        __builtin_amdgcn_sched_barrier(0);

        // ---- phase 1: A m0-3 k0 + B k0 ; stage B1(t+1)
        #pragma unroll
        for (int m = 0; m < 4; ++m) af[m] = *(const short8*)(&As[s][wr][aoff[m][0]]);
        #pragma unroll
        for (int n = 0; n < 4; ++n) bf[n] = *(const short8*)(&Bs[s][bh][boff[n][0]]);
        if (t + 1 < NT) SB_(t + 1, 1);
        __builtin_amdgcn_s_barrier();
        asm volatile("s_waitcnt lgkmcnt(0)" ::: "memory");
        __builtin_amdgcn_sched_barrier(0);
        __builtin_amdgcn_s_setprio(1);
        #pragma unroll
        for (int m = 0; m < 4; ++m)
            #pragma unroll
            for (int n = 0; n < 4; ++n)
                acc[m][n] = __builtin_amdgcn_mfma_f32_16x16x32_bf16(af[m], bf[n], acc[m][n], 0, 0, 0);
        __builtin_amdgcn_s_setprio(0);
        __builtin_amdgcn_s_barrier();

        // ---- phase 2: A m4-7 k0 (B reused) ; stage A0(t+1)
        #pragma unroll
        for (int m = 0; m < 4; ++m) af[m] = *(const short8*)(&As[s][wr][aoff[4 + m][0]]);
        if (t + 1 < NT) SA_(t + 1, 0);
        __builtin_amdgcn_s_barrier();
        asm volatile("s_waitcnt lgkmcnt(0)" ::: "memory");
        __builtin_amdgcn_sched_barrier(0);
        __builtin_amdgcn_s_setprio(1);
        #pragma unroll
        for (int m = 0; m < 4; ++m)
            #pragma unroll
            for (int n = 0; n < 4; ++n)
                acc[4 + m][n] = __builtin_amdgcn_mfma_f32_16x16x32_bf16(af[m], bf[n], acc[4 + m][n], 0, 0, 0);
        __builtin_amdgcn_s_setprio(0);
        __builtin_amdgcn_s_barrier();

        // ---- phase 3: A m0-3 k1 + B k1 ; stage A1(t+1)
        #pragma unroll
        for (int m = 0; m < 4; ++m) af[m] = *(const short8*)(&As[s][wr][aoff[m][1]]);
        #pragma unroll
        for (int n = 0; n < 4; ++n) bf[n] = *(const short8*)(&Bs[s][bh][boff[n][1]]);
        if (t + 1 < NT) SA_(t + 1, 1);
        __builtin_amdgcn_s_barrier();
        asm volatile("s_waitcnt lgkmcnt(0)" ::: "memory");
        __builtin_amdgcn_sched_barrier(0);
        __builtin_amdgcn_s_setprio(1);
        #pragma unroll
        for (int m = 0; m < 4; ++m)
            #pragma unroll
            for (int n = 0; n < 4; ++n)
                acc[m][n] = __builtin_amdgcn_mfma_f32_16x16x32_bf16(af[m], bf[n], acc[m][n], 0, 0, 0);
        __builtin_amdgcn_s_setprio(0);
        __builtin_amdgcn_s_barrier();

        // ---- phase 4: A m4-7 k1 ; stage B0(t+2); trailing sync is loop-top
        #pragma unroll
        for (int m = 0; m < 4; ++m) af[m] = *(const short8*)(&As[s][wr][aoff[4 + m][1]]);
        if (t + 2 < NT) SB_(t + 2, 0);
        __builtin_amdgcn_s_barrier();
        asm volatile("s_waitcnt lgkmcnt(0)" ::: "memory");
        __builtin_amdgcn_sched_barrier(0);
        __builtin_amdgcn_s_setprio(1);
        #pragma unroll
        for (int m = 0; m < 4; ++m)
            #pragma unroll
            for (int n = 0; n < 4; ++n)
                acc[4 + m][n] = __builtin_amdgcn_mfma_f32_16x16x32_bf16(af[m], bf[n], acc[4 + m][n], 0, 0, 0);
        __builtin_amdgcn_s_setprio(0);
    }

    // epilogue: LDS bounce -> f32x4 stores, +bias
    __syncthreads();
    float* patch = (float*)((wv & 4) ? (void*)&Bs[0][0][0] : (void*)&As[0][0][0])
                   + (wv & 3) * (16 * 68);
    const int cc0 = n0 + wc * 64;
    const f32x4 bvv = *(const f32x4*)(bias + cc0 + (lane & 15) * 4);
    #pragma unroll
    for (int m = 0; m < 8; ++m) {
        #pragma unroll
        for (int n = 0; n < 4; ++n)
            #pragma unroll
            for (int i = 0; i < 4; ++i)
                patch[(ks4 * 4 + i) * 68 + n * 16 + lrow] = acc[m][n][i];
        #pragma unroll
        for (int i2 = 0; i2 < 4; ++i2) {
            const int prow = i2 * 4 + ks4;
            f32x4 v = *(const f32x4*)(patch + prow * 68 + (lane & 15) * 4) + bvv;
            const int rr = m0 + wr * 128 + m * 16 + prow;
            *(f32x4*)(C + (size_t)rr * N + cc0 + (lane & 15) * 4) = v;
        }
    }
}

// ---------------------------------------------------------------------------
// Flash attention v4 (r5-exact): swapped-operand S^T = mfma(K,Q), scalar m/l,
// b64 P-stores, V^T staged via global_load_lds, double-buffered K/V.
__global__ __launch_bounds__(256, 2) void attn_flash4(
    const u16* __restrict__ qk, const u16* __restrict__ vT, float* __restrict__ delta)
{
    __shared__ __align__(16) u16 Qs[64 * 64];
    __shared__ __align__(16) u16 Kd[2][64 * 64];
    __shared__ __align__(16) u16 Vd[2][64 * 64];
    __shared__ __align__(16) u16 Ps[4][16 * 64];

    const int pair = blockIdx.x, h = blockIdx.y, b = blockIdx.z;
    const int tid = threadIdx.x, wv = tid >> 6, lane = tid & 63;
    const int lrow = lane & 15, ks4 = lane >> 4, li4 = ks4 * 4;
    const long baseQK = (long)b * NS * 2048;
    const u16* vbase = vT + (long)h * 64 * 2048 + b * NS;
    u16* ps = &Ps[wv][0];

    for (int rep = 0; rep < 2; ++rep) {
        const int qt = rep ? 15 - pair : pair;
        __syncthreads();

        #pragma unroll
        for (int i = 0; i < 2; ++i) {
            const int c = (wv * 2 + i) * 64 + lane;
            const int row = c >> 3, u = (c & 7) ^ (row & 7);
            GLL16(qk + baseQK + (long)(qt * 64 + row) * 2048 + h * 64 + u * 8, Qs + c * 8);
            GLL16(qk + baseQK + (long)row * 2048 + 1024 + h * 64 + u * 8, Kd[0] + c * 8);
            GLL16(vbase + (long)row * 2048 + u * 8, Vd[0] + c * 8);
        }
        __syncthreads();

        short8 aq[2];
        {
            const int row = wv * 16 + lrow;
            aq[0] = *(const short8*)(Qs + row * 64 + ((ks4 ^ (row & 7)) * 8));
            aq[1] = *(const short8*)(Qs + row * 64 + (((4 + ks4) ^ (row & 7)) * 8));
        }

        f32x4 o[4] = {};
        float m_ = -__builtin_inff(), l_ = 0.f;

        for (int t = 0; t <= qt; ++t) {
            const int p = t & 1;
            if (t < qt) {
                #pragma unroll
                for (int i = 0; i < 2; ++i) {
                    const int c = (wv * 2 + i) * 64 + lane;
                    const int row = c >> 3, u = (c & 7) ^ (row & 7);
                    GLL16(qk + baseQK + (long)((t + 1) * 64 + row) * 2048 + 1024 + h * 64 + u * 8, Kd[p ^ 1] + c * 8);
                    GLL16(vbase + (long)row * 2048 + (t + 1) * 64 + u * 8, Vd[p ^ 1] + c * 8);
                }
            }
            f32x4 sa[4];
            #pragma unroll
            for (int nb = 0; nb < 4; ++nb) {
                f32x4 z = {};
                #pragma unroll
                for (int kd = 0; kd < 2; ++kd) {
                    const int row = nb * 16 + lrow;
                    short8 bk = *(const short8*)(Kd[p] + row * 64 + (((kd * 4 + ks4) ^ (row & 7)) * 8));
                    z = __builtin_amdgcn_mfma_f32_16x16x32_bf16(bk, aq[kd], z, 0, 0, 0);
                }
                sa[nb] = z;
            }
            const int qg = qt * 64 + wv * 16 + lrow;
            #pragma unroll
            for (int nb = 0; nb < 4; ++nb)
                #pragma unroll
                for (int i = 0; i < 4; ++i) {
                    float sc = sa[nb][i] * 0.125f;
                    if (t == qt && (t * 64 + nb * 16 + li4 + i) > qg) sc = -__builtin_inff();
                    sa[nb][i] = sc;
                }
            float mt = sa[0][0];
            #pragma unroll
            for (int nb = 0; nb < 4; ++nb)
                #pragma unroll
                for (int i = 0; i < 4; ++i) mt = fmaxf(mt, sa[nb][i]);
            mt = fmaxf(mt, __shfl_xor(mt, 16, 64));
            mt = fmaxf(mt, __shfl_xor(mt, 32, 64));
            const float mn = fmaxf(m_, mt);
            const float fac = expf(m_ - mn);
            m_ = mn;
            float rs = 0.f;
            #pragma unroll
            for (int nb = 0; nb < 4; ++nb)
                #pragma unroll
                for (int i = 0; i < 4; ++i) {
                    float pp = expf(sa[nb][i] - mn);
                    sa[nb][i] = pp; rs += pp;
                }
            rs += __shfl_xor(rs, 16, 64);
            rs += __shfl_xor(rs, 32, 64);
            l_ = l_ * fac + rs;
            #pragma unroll
            for (int nd = 0; nd < 4; ++nd) o[nd] *= fac;

            #pragma unroll
            for (int nb = 0; nb < 4; ++nb) {
                u16 fourv[4];
                #pragma unroll
                for (int i = 0; i < 4; ++i) fourv[i] = f2b(sa[nb][i]);
                const int kvb = nb * 16 + li4;
                const int addr = lrow * 64 + (((kvb >> 3) ^ (lrow & 7)) * 8) + (kvb & 7);
                *(short4_t*)(ps + addr) = *(const short4_t*)fourv;
            }
            short8 pa[2];
            pa[0] = *(const short8*)(ps + lrow * 64 + ((ks4 ^ (lrow & 7)) * 8));
            pa[1] = *(const short8*)(ps + lrow * 64 + (((4 + ks4) ^ (lrow & 7)) * 8));
            #pragma unroll
            for (int nd = 0; nd < 4; ++nd)
                #pragma unroll
                for (int kd = 0; kd < 2; ++kd) {
                    const int row = nd * 16 + lrow;
                    short8 vb = *(const short8*)(Vd[p] + row * 64 + (((kd * 4 + ks4) ^ (row & 7)) * 8));
                    o[nd] = __builtin_amdgcn_mfma_f32_16x16x32_bf16(vb, pa[kd], o[nd], 0, 0, 0);
                }
            __syncthreads();
        }

        const float inv = 1.f / l_;
        const long tok = (long)b * NS + qt * 64 + wv * 16 + lrow;
        #pragma unroll
        for (int nd = 0; nd < 4; ++nd) {
            f32x4 v = o[nd] * inv;
            *(f32x4*)(delta + tok * DMODEL + h * 64 + nd * 16 + li4) = v;
        }
    }
}

// ---------------------------------------------------------------------------
extern "C" void kernel_launch(void* const* d_in, const int* in_sizes, int n_in,
                              void* d_out, int out_size, void* d_ws, size_t ws_size,
                              hipStream_t stream) {
    const int*   toks  = (const int*)d_in[0];
    const float* emb   = (const float*)d_in[1];
    const float* Wq    = (const float*)d_in[2];
    const float* Wk    = (const float*)d_in[3];
    const float* Wv    = (const float*)d_in[4];
    const float* W1    = (const float*)d_in[5];
    const float* W2    = (const float*)d_in[6];
    const float* ln1g  = (const float*)d_in[7];
    const float* ln1b  = (const float*)d_in[8];
    const float* ln2g  = (const float*)d_in[9];
    const float* ln2b  = (const float*)d_in[10];
    const float* Wout  = (const float*)d_in[11];
    const float* bout  = (const float*)d_in[12];

    char* p = (char*)d_ws;
    auto alloc = [&](size_t bytes) { void* r = (void*)p; p += (bytes + 255) & ~(size_t)255; return r; };
    const size_t PSZ = (size_t)MTOK * 1024;          // one f32 partial, elements
    u16*   Wqkv_t = (u16*)alloc((size_t)NLAYER * 3072 * 1024 * 2);
    u16*   W1t    = (u16*)alloc((size_t)NLAYER * 4096 * 1024 * 2);
    u16*   W2t    = (u16*)alloc((size_t)NLAYER * 1024 * 4096 * 2);
    u16*   Woutt  = (u16*)alloc((size_t)NVOCAB * 1024 * 2);
    float* x      = (float*)alloc((size_t)MTOK * 1024 * 4);
    u16*   xb     = (u16*)alloc((size_t)MTOK * 1024 * 2);
    u16*   qkbuf  = (u16*)alloc((size_t)MTOK * 2048 * 2);
    u16*   vTbuf  = (u16*)alloc((size_t)1024 * MTOK * 2);
    u16*   hbuf   = (u16*)alloc((size_t)MTOK * 4096 * 2);
    float* dbuf   = (float*)alloc(PSZ * 2 * 4);      // 2 split-K partials

    float* hbufF = (float*)hbuf;                     // attn output (region dead then)

    transpose_qkv<<<dim3(2, 32, 96), dim3(32, 8), 0, stream>>>(Wq, Wqkv_t, 0);
    transpose_qkv<<<dim3(2, 32, 96), dim3(32, 8), 0, stream>>>(Wk, Wqkv_t, 1);
    transpose_qkv<<<dim3(2, 32, 96), dim3(32, 8), 0, stream>>>(Wv, Wqkv_t, 2);
    trans64<<<dim3(64, 16, 6), 256, 0, stream>>>(W1, W1t, 1024, 4096, 1024l * 4096, 4096l * 1024);
    trans64<<<dim3(16, 64, 6), 256, 0, stream>>>(W2, W2t, 4096, 1024, 4096l * 1024, 1024l * 4096);
    trans64<<<dim3(500, 16, 1), 256, 0, stream>>>(Wout, Woutt, 1024, NVOCAB, 0, 0);

    embed_pe<<<MTOK, 256, 0, stream>>>(toks, emb, x, xb);

    for (int l = 0; l < NLAYER; ++l) {
        const u16* Wl = Wqkv_t + (size_t)l * 3072 * 1024;
        gemm_pipe<128, 1><<<dim3(16 * 16), 256, 0, stream>>>(
            xb, Wl, qkbuf, nullptr, MTOK, 2048, 1024, 1024, 1024, 0);
        gemm_pipe<128, 1><<<dim3(8 * 16), 256, 0, stream>>>(
            Wl + (size_t)2048 * 1024, xb, vTbuf, nullptr, 1024, MTOK, 1024, 1024, 1024, 0);
        attn_flash4<<<dim3(8, NH, NB), 256, 0, stream>>>(qkbuf, vTbuf, hbufF);
        ln_residual<1><<<MTOK, 256, 0, stream>>>(x, hbufF, 0,
            ln1g + l * 1024, ln1b + l * 1024, x, xb);
        gemm_pipe<128, 2><<<dim3(16 * 32), 256, 0, stream>>>(
            xb, W1t + (size_t)l * 4096 * 1024, hbuf, nullptr, MTOK, 4096, 1024, 1024, 1024, 0);
        gemm_pipe<128, 0><<<dim3(16 * 8, 2), 256, 0, stream>>>(
            hbuf, W2t + (size_t)l * 1024 * 4096, dbuf, nullptr, MTOK, 1024, 2048, 4096, 4096, PSZ);
        ln_residual<2><<<MTOK, 256, 0, stream>>>(x, dbuf, PSZ,
            ln2g + l * 1024, ln2b + l * 1024, x, xb);
    }

    gemm8p<<<dim3(1000), 512, 0, stream>>>(
        xb, Woutt, (float*)d_out, bout, MTOK, NVOCAB, 1024);
}

// Round 8
// 1114.714 us; speedup vs baseline: 1.0853x; 1.0853x over previous
//
#include <hip/hip_runtime.h>

typedef unsigned short u16;
typedef __attribute__((ext_vector_type(8))) short short8;
typedef __attribute__((ext_vector_type(4))) short short4_t;
typedef __attribute__((ext_vector_type(4))) float f32x4;

#define NLAYER 6
#define NH 16
#define DMODEL 1024
#define DHEAD 64
#define NVOCAB 32000
#define NB 2
#define NS 1024
#define NDFF 4096
#define MTOK (NB*NS)   // 2048

__device__ __forceinline__ u16 f2b(float f) {
    union { float f; unsigned u; } x; x.f = f;
    unsigned r = x.u + 0x7fffu + ((x.u >> 16) & 1u);
    return (u16)(r >> 16);
}

#define GLL16(gp, lp) __builtin_amdgcn_global_load_lds( \
    (const __attribute__((address_space(1))) void*)(gp), \
    (__attribute__((address_space(3))) void*)(lp), 16, 0, 0)

// ---------------------------------------------------------------------------
__global__ __launch_bounds__(256) void trans64(
    const float* __restrict__ src, u16* __restrict__ dst,
    int R, int C, long sStride, long dStride)
{
    __shared__ float sh[64][65];
    const int c0 = blockIdx.x * 64, r0 = blockIdx.y * 64;
    const float* s = src + (long)blockIdx.z * sStride;
    u16* d = dst + (long)blockIdx.z * dStride;
    const int tid = threadIdx.x;
    const int lr = tid >> 4, lc = (tid & 15) * 4;
    #pragma unroll
    for (int q = 0; q < 4; ++q) {
        const float4 v = *(const float4*)(s + (long)(r0 + q * 16 + lr) * C + c0 + lc);
        sh[q * 16 + lr][lc + 0] = v.x;
        sh[q * 16 + lr][lc + 1] = v.y;
        sh[q * 16 + lr][lc + 2] = v.z;
        sh[q * 16 + lr][lc + 3] = v.w;
    }
    __syncthreads();
    #pragma unroll
    for (int k = 0; k < 2; ++k) {
        const int t = tid + 256 * k;
        const int col = t >> 3, rch = (t & 7) * 8;
        u16 tmp[8];
        #pragma unroll
        for (int j = 0; j < 8; ++j) tmp[j] = f2b(sh[rch + j][col]);
        *(short8*)(d + (long)(c0 + col) * R + r0 + rch) = *(const short8*)tmp;
    }
}

__global__ void transpose_qkv(const float* __restrict__ src, u16* __restrict__ dst, int sel)
{
    __shared__ float t[32][33];
    const int bi = blockIdx.z, l = bi >> 4, h = bi & 15;
    const float* s = src + (long)bi * (DMODEL * DHEAD);
    u16* d = dst + (long)l * 3072 * DMODEL + (long)(sel * 1024 + h * 64) * DMODEL;
    const int c0 = blockIdx.x * 32, r0 = blockIdx.y * 32;
    const int tx = threadIdx.x, ty = threadIdx.y;
    #pragma unroll
    for (int j = 0; j < 32; j += 8)
        t[ty + j][tx] = s[(long)(r0 + ty + j) * DHEAD + c0 + tx];
    __syncthreads();
    #pragma unroll
    for (int j = 0; j < 32; j += 8)
        d[(long)(c0 + ty + j) * DMODEL + r0 + tx] = f2b(t[tx][ty + j]);
}

// ---------------------------------------------------------------------------
__global__ void embed_pe(const int* __restrict__ toks, const float* __restrict__ emb,
                         float* __restrict__ x, u16* __restrict__ xb)
{
    const int row = blockIdx.x;
    const int s = row & (NS - 1);
    const long erow = (long)toks[row] * DMODEL;
    const long base = (long)row * DMODEL;
    #pragma unroll
    for (int j = 0; j < 4; ++j) {
        int d = threadIdx.x + j * 256;
        float ang = (float)s * exp2f(-(float)d * (9.965784284662087f / 1024.f));
        float pe = (d & 1) ? cosf(ang) : sinf(ang);
        float v = emb[erow + d] + pe;
        x[base + d] = v;
        xb[base + d] = f2b(v);
    }
}

// ---------------------------------------------------------------------------
template<int ND>
__global__ __launch_bounds__(256) void ln_residual(
    const float* __restrict__ xin, const float* __restrict__ delta, size_t pstride,
    const float* __restrict__ g, const float* __restrict__ bb,
    float* __restrict__ xout, u16* __restrict__ xbout)
{
    __shared__ float red[8];
    const long base = (long)blockIdx.x * DMODEL;
    const int d = threadIdx.x * 4;
    f32x4 v = *(const f32x4*)(xin + base + d);
    #pragma unroll
    for (int y = 0; y < ND; ++y)
        v += *(const f32x4*)(delta + base + (size_t)y * pstride + d);
    float sum = v[0] + v[1] + v[2] + v[3];
    float sq  = v[0]*v[0] + v[1]*v[1] + v[2]*v[2] + v[3]*v[3];
    #pragma unroll
    for (int off = 1; off < 64; off <<= 1) {
        sum += __shfl_xor(sum, off, 64);
        sq  += __shfl_xor(sq,  off, 64);
    }
    const int wv = threadIdx.x >> 6, lane = threadIdx.x & 63;
    if (lane == 0) { red[wv] = sum; red[4 + wv] = sq; }
    __syncthreads();
    float ts = red[0] + red[1] + red[2] + red[3];
    float tq = red[4] + red[5] + red[6] + red[7];
    float mu = ts * (1.f / DMODEL);
    float var = tq * (1.f / DMODEL) - mu * mu;
    float rstd = rsqrtf(var + 1e-5f);
    const f32x4 gg = *(const f32x4*)(g + d);
    const f32x4 bv = *(const f32x4*)(bb + d);
    f32x4 yv = (v - mu) * rstd * gg + bv;
    *(f32x4*)(xout + base + d) = yv;
    u16 fourv[4];
    #pragma unroll
    for (int i = 0; i < 4; ++i) fourv[i] = f2b(yv[i]);
    *(short4_t*)(xbout + base + d) = *(const short4_t*)fourv;
}

// ---------------------------------------------------------------------------
// r5-proven pipelined GEMM body (16x16x32, BK=32, 4 LDS slots, vmcnt(8),
// XOR swizzle, XCD swizzle). Shared arrays passed in (so kernels can merge).
template<int BM, int EPI>
__device__ __forceinline__ void gemm_body(
    const u16* __restrict__ A, const u16* __restrict__ Bt,
    void* __restrict__ Cout, const float* __restrict__ bias,
    int M, int N, int K, int lda, int ldb, size_t zstride,
    int id, int nwg, int zidx, u16* Asp, u16* Bsp)
{
    constexpr int WAVES = BM / 32;
    constexpr int WC = WAVES / 2;
    constexpr int MR = BM / 32;
    constexpr int TILE = BM * 32;

    const int nmb = M / BM;
    const int q = nwg >> 3, r = nwg & 7, xcd = id & 7, loc = id >> 3;
    const int swz = (xcd < r ? xcd * (q + 1) : r * (q + 1) + (xcd - r) * q) + loc;
    const int m0 = (swz % nmb) * BM, n0 = (swz / nmb) * BM;
    const int koff = zidx * K;

    const int tid = threadIdx.x, wv = tid >> 6, lane = tid & 63;
    const int wr = wv / WC, wc = wv % WC;
    const int lrow = lane & 15, ks = lane >> 4;

    const u16* gsrc[4];
    int ldso[2];
    {
        const int l4 = lane >> 2, s = lane & 3;
        #pragma unroll
        for (int j = 0; j < 2; ++j) {
            const int row = j * (WAVES * 16) + wv * 16 + l4;
            const int x = (row >> 1) & 3;
            gsrc[j]     = A  + (size_t)(m0 + row) * lda + koff + (size_t)((s ^ x) * 8);
            gsrc[2 + j] = Bt + (size_t)(n0 + row) * ldb + koff + (size_t)((s ^ x) * 8);
            ldso[j] = (j * (WAVES * 16) + wv * 16) * 32;
        }
    }
    int aoff[MR], boff[4];
    #pragma unroll
    for (int m = 0; m < MR; ++m) {
        const int row = wr * (BM / 2) + m * 16 + lrow;
        aoff[m] = row * 32 + ((ks ^ ((row >> 1) & 3)) * 8);
    }
    #pragma unroll
    for (int n = 0; n < 4; ++n) {
        const int row = wc * 64 + n * 16 + lrow;
        boff[n] = row * 32 + ((ks ^ ((row >> 1) & 3)) * 8);
    }

    const int NT = K / 32;
    auto ISSUE = [&](int t) {
        const int b = t & 3;
        const size_t ko = (size_t)t * 32;
        #pragma unroll
        for (int j = 0; j < 2; ++j) {
            GLL16(gsrc[j] + ko,     Asp + b * TILE + ldso[j]);
            GLL16(gsrc[2 + j] + ko, Bsp + b * TILE + ldso[j]);
        }
    };

    f32x4 acc[MR][4] = {};
    ISSUE(0); ISSUE(1); ISSUE(2);

    for (int t = 0; t < NT; ++t) {
        if (t < NT - 2)       { asm volatile("s_waitcnt vmcnt(8)" ::: "memory"); }
        else if (t == NT - 2) { asm volatile("s_waitcnt vmcnt(4)" ::: "memory"); }
        else                  { asm volatile("s_waitcnt vmcnt(0)" ::: "memory"); }
        __builtin_amdgcn_sched_barrier(0);
        __builtin_amdgcn_s_barrier();
        __builtin_amdgcn_sched_barrier(0);

        const int b = t & 3;
        short8 af[MR], bf[4];
        #pragma unroll
        for (int m = 0; m < MR; ++m) af[m] = *(const short8*)(Asp + b * TILE + aoff[m]);
        #pragma unroll
        for (int n = 0; n < 4; ++n)  bf[n] = *(const short8*)(Bsp + b * TILE + boff[n]);
        if (t + 3 < NT) ISSUE(t + 3);
        __builtin_amdgcn_s_setprio(1);
        #pragma unroll
        for (int m = 0; m < MR; ++m)
            #pragma unroll
            for (int n = 0; n < 4; ++n)
                acc[m][n] = __builtin_amdgcn_mfma_f32_16x16x32_bf16(af[m], bf[n], acc[m][n], 0, 0, 0);
        __builtin_amdgcn_s_setprio(0);
    }

    if (EPI == 0 || EPI == 3) {
        __syncthreads();
        float* patch = (float*)((WAVES == 8 && (wv & 4)) ? (void*)Bsp : (void*)Asp)
                       + (wv & 3) * (16 * 68);
        const int cc0 = n0 + wc * 64;
        f32x4 bvv = {};
        if (EPI == 3) bvv = *(const f32x4*)(bias + cc0 + (lane & 15) * 4);
        float* C = (float*)Cout + (EPI == 0 ? (size_t)zidx * zstride : (size_t)0);
        #pragma unroll
        for (int m = 0; m < MR; ++m) {
            #pragma unroll
            for (int n = 0; n < 4; ++n)
                #pragma unroll
                for (int i = 0; i < 4; ++i)
                    patch[(ks * 4 + i) * 68 + n * 16 + lrow] = acc[m][n][i];
            #pragma unroll
            for (int i2 = 0; i2 < 4; ++i2) {
                const int prow = i2 * 4 + ks;
                f32x4 v = *(const f32x4*)(patch + prow * 68 + (lane & 15) * 4);
                if (EPI == 3) v += bvv;
                const int rr = m0 + wr * (BM / 2) + m * 16 + prow;
                *(f32x4*)(C + (size_t)rr * N + cc0 + (lane & 15) * 4) = v;
            }
        }
    } else {
        u16* C = (u16*)Cout;
        #pragma unroll
        for (int m = 0; m < MR; ++m) {
            const int rr = m0 + wr * (BM / 2) + m * 16 + ks * 4;
            #pragma unroll
            for (int n = 0; n < 4; ++n) {
                const int cc = n0 + wc * 64 + n * 16 + lrow;
                #pragma unroll
                for (int i = 0; i < 4; ++i) {
                    float vv = acc[m][n][i];
                    if (EPI == 2) vv = fmaxf(vv, 0.f);
                    C[(size_t)(rr + i) * N + cc] = f2b(vv);
                }
            }
        }
    }
}

template<int BM, int EPI>
__global__ __launch_bounds__(BM*2, 2) void gemm_pipe(
    const u16* __restrict__ A, const u16* __restrict__ Bt,
    void* __restrict__ Cout, const float* __restrict__ bias,
    int M, int N, int K, int lda, int ldb, size_t zstride)
{
    __shared__ __align__(16) u16 As[4][BM * 32];
    __shared__ __align__(16) u16 Bs[4][BM * 32];
    gemm_body<BM, EPI>(A, Bt, Cout, bias, M, N, K, lda, ldb, zstride,
                       blockIdx.x, gridDim.x, blockIdx.y, &As[0][0], &Bs[0][0]);
}

// Merged per-layer projection: blocks 0..255 = qk GEMM, 256..383 = vT GEMM
__global__ __launch_bounds__(256, 2) void gemm_qkv(
    const u16* __restrict__ xb, const u16* __restrict__ Wl,
    u16* __restrict__ qkbuf, u16* __restrict__ vTbuf)
{
    __shared__ __align__(16) u16 As[4][128 * 32];
    __shared__ __align__(16) u16 Bs[4][128 * 32];
    if (blockIdx.x < 256)
        gemm_body<128, 1>(xb, Wl, qkbuf, nullptr, MTOK, 2048, 1024, 1024, 1024, 0,
                          blockIdx.x, 256, 0, &As[0][0], &Bs[0][0]);
    else
        gemm_body<128, 1>(Wl + (size_t)2048 * 1024, xb, vTbuf, nullptr, 1024, MTOK, 1024,
                          1024, 1024, 0, blockIdx.x - 256, 128, 0, &As[0][0], &Bs[0][0]);
}

// ---------------------------------------------------------------------------
// Vocab GEMM: 128x256 tile, 4 waves, BK=32, 2 LDS slots (48KB) -> 2 blocks/CU
// so epilogue/prologue of one block overlap the K-loop of the other.
__global__ __launch_bounds__(256, 2) void gemm_voc(
    const u16* __restrict__ A, const u16* __restrict__ Bt,
    float* __restrict__ C, const float* __restrict__ bias,
    int M, int N, int K)
{
    __shared__ __align__(16) u16 As[2][128 * 32];
    __shared__ __align__(16) u16 Bs[2][256 * 32];

    const int nmb = M >> 7;                   // 16
    const int id = blockIdx.x, nwg = gridDim.x;
    const int q = nwg >> 3, r = nwg & 7, xcd = id & 7, loc = id >> 3;
    const int swz = (xcd < r ? xcd * (q + 1) : r * (q + 1) + (xcd - r) * q) + loc;
    const int m0 = (swz % nmb) * 128, n0 = (swz / nmb) * 256;

    const int tid = threadIdx.x, wv = tid >> 6, lane = tid & 63;
    const int wr = wv >> 1, wc = wv & 1;
    const int lrow = lane & 15, ks = lane >> 4;

    const u16* srcA[2]; int dsoA[2];
    const u16* srcB[4]; int dsoB[4];
    #pragma unroll
    for (int i = 0; i < 2; ++i) {
        const int c = tid + i * 256, row = c >> 2, s = c & 3;
        srcA[i] = A + (size_t)(m0 + row) * K + (size_t)(((s ^ ((row >> 1) & 3))) * 8);
        dsoA[i] = c * 8;
    }
    #pragma unroll
    for (int i = 0; i < 4; ++i) {
        const int c = tid + i * 256, row = c >> 2, s = c & 3;
        srcB[i] = Bt + (size_t)(n0 + row) * K + (size_t)(((s ^ ((row >> 1) & 3))) * 8);
        dsoB[i] = c * 8;
    }
    int aoff[4], boff[8];
    #pragma unroll
    for (int m = 0; m < 4; ++m) {
        const int row = wr * 64 + m * 16 + lrow;
        aoff[m] = row * 32 + ((ks ^ ((row >> 1) & 3)) * 8);
    }
    #pragma unroll
    for (int n = 0; n < 8; ++n) {
        const int row = wc * 128 + n * 16 + lrow;
        boff[n] = row * 32 + ((ks ^ ((row >> 1) & 3)) * 8);
    }

    const int NT = K >> 5;                    // 32
    auto ISSUE = [&](int t) {
        const int b = t & 1;
        const size_t ko = (size_t)t * 32;
        #pragma unroll
        for (int i = 0; i < 2; ++i) GLL16(srcA[i] + ko, &As[b][dsoA[i]]);
        #pragma unroll
        for (int i = 0; i < 4; ++i) GLL16(srcB[i] + ko, &Bs[b][dsoB[i]]);
    };

    f32x4 acc[4][8] = {};
    ISSUE(0); ISSUE(1);

    for (int t = 0; t < NT; ++t) {
        if (t < NT - 1) { asm volatile("s_waitcnt vmcnt(6)" ::: "memory"); }
        else            { asm volatile("s_waitcnt vmcnt(0)" ::: "memory"); }
        __builtin_amdgcn_sched_barrier(0);
        __builtin_amdgcn_s_barrier();
        __builtin_amdgcn_sched_barrier(0);

        const int b = t & 1;
        short8 af[4], bf[8];
        #pragma unroll
        for (int m = 0; m < 4; ++m) af[m] = *(const short8*)(&As[b][aoff[m]]);
        #pragma unroll
        for (int n = 0; n < 8; ++n) bf[n] = *(const short8*)(&Bs[b][boff[n]]);
        asm volatile("s_waitcnt lgkmcnt(0)" ::: "memory");
        __builtin_amdgcn_sched_barrier(0);
        __builtin_amdgcn_s_barrier();        // all reads of slot b done
        __builtin_amdgcn_sched_barrier(0);
        if (t + 2 < NT) ISSUE(t + 2);
        __builtin_amdgcn_s_setprio(1);
        #pragma unroll
        for (int m = 0; m < 4; ++m)
            #pragma unroll
            for (int n = 0; n < 8; ++n)
                acc[m][n] = __builtin_amdgcn_mfma_f32_16x16x32_bf16(af[m], bf[n], acc[m][n], 0, 0, 0);
        __builtin_amdgcn_s_setprio(0);
    }

    // epilogue: per-wave 16x136 f32 patch -> f32x4 stores (+bias)
    __syncthreads();
    float* patch = (wv == 0) ? (float*)&As[0][0]
                             : (float*)&Bs[0][0] + (wv - 1) * (16 * 136);
    const int cc0 = n0 + wc * 128;
    const int l32 = lane & 31, lh = lane >> 5;
    const f32x4 bvv = *(const f32x4*)(bias + cc0 + l32 * 4);
    #pragma unroll
    for (int m = 0; m < 4; ++m) {
        #pragma unroll
        for (int n = 0; n < 8; ++n)
            #pragma unroll
            for (int i = 0; i < 4; ++i)
                patch[(ks * 4 + i) * 136 + n * 16 + lrow] = acc[m][n][i];
        #pragma unroll
        for (int j = 0; j < 8; ++j) {
            const int prow = j * 2 + lh;
            f32x4 v = *(const f32x4*)(patch + prow * 136 + l32 * 4) + bvv;
            const int rr = m0 + wr * 64 + m * 16 + prow;
            *(f32x4*)(C + (size_t)rr * N + cc0 + l32 * 4) = v;
        }
    }
}

// ---------------------------------------------------------------------------
// Flash attention v4 (r5-exact)
__global__ __launch_bounds__(256, 2) void attn_flash4(
    const u16* __restrict__ qk, const u16* __restrict__ vT, float* __restrict__ delta)
{
    __shared__ __align__(16) u16 Qs[64 * 64];
    __shared__ __align__(16) u16 Kd[2][64 * 64];
    __shared__ __align__(16) u16 Vd[2][64 * 64];
    __shared__ __align__(16) u16 Ps[4][16 * 64];

    const int pair = blockIdx.x, h = blockIdx.y, b = blockIdx.z;
    const int tid = threadIdx.x, wv = tid >> 6, lane = tid & 63;
    const int lrow = lane & 15, ks4 = lane >> 4, li4 = ks4 * 4;
    const long baseQK = (long)b * NS * 2048;
    const u16* vbase = vT + (long)h * 64 * 2048 + b * NS;
    u16* ps = &Ps[wv][0];

    for (int rep = 0; rep < 2; ++rep) {
        const int qt = rep ? 15 - pair : pair;
        __syncthreads();

        #pragma unroll
        for (int i = 0; i < 2; ++i) {
            const int c = (wv * 2 + i) * 64 + lane;
            const int row = c >> 3, u = (c & 7) ^ (row & 7);
            GLL16(qk + baseQK + (long)(qt * 64 + row) * 2048 + h * 64 + u * 8, Qs + c * 8);
            GLL16(qk + baseQK + (long)row * 2048 + 1024 + h * 64 + u * 8, Kd[0] + c * 8);
            GLL16(vbase + (long)row * 2048 + u * 8, Vd[0] + c * 8);
        }
        __syncthreads();

        short8 aq[2];
        {
            const int row = wv * 16 + lrow;
            aq[0] = *(const short8*)(Qs + row * 64 + ((ks4 ^ (row & 7)) * 8));
            aq[1] = *(const short8*)(Qs + row * 64 + (((4 + ks4) ^ (row & 7)) * 8));
        }

        f32x4 o[4] = {};
        float m_ = -__builtin_inff(), l_ = 0.f;

        for (int t = 0; t <= qt; ++t) {
            const int p = t & 1;
            if (t < qt) {
                #pragma unroll
                for (int i = 0; i < 2; ++i) {
                    const int c = (wv * 2 + i) * 64 + lane;
                    const int row = c >> 3, u = (c & 7) ^ (row & 7);
                    GLL16(qk + baseQK + (long)((t + 1) * 64 + row) * 2048 + 1024 + h * 64 + u * 8, Kd[p ^ 1] + c * 8);
                    GLL16(vbase + (long)row * 2048 + (t + 1) * 64 + u * 8, Vd[p ^ 1] + c * 8);
                }
            }
            f32x4 sa[4];
            #pragma unroll
            for (int nb = 0; nb < 4; ++nb) {
                f32x4 z = {};
                #pragma unroll
                for (int kd = 0; kd < 2; ++kd) {
                    const int row = nb * 16 + lrow;
                    short8 bk = *(const short8*)(Kd[p] + row * 64 + (((kd * 4 + ks4) ^ (row & 7)) * 8));
                    z = __builtin_amdgcn_mfma_f32_16x16x32_bf16(bk, aq[kd], z, 0, 0, 0);
                }
                sa[nb] = z;
            }
            const int qg = qt * 64 + wv * 16 + lrow;
            #pragma unroll
            for (int nb = 0; nb < 4; ++nb)
                #pragma unroll
                for (int i = 0; i < 4; ++i) {
                    float sc = sa[nb][i] * 0.125f;
                    if (t == qt && (t * 64 + nb * 16 + li4 + i) > qg) sc = -__builtin_inff();
                    sa[nb][i] = sc;
                }
            float mt = sa[0][0];
            #pragma unroll
            for (int nb = 0; nb < 4; ++nb)
                #pragma unroll
                for (int i = 0; i < 4; ++i) mt = fmaxf(mt, sa[nb][i]);
            mt = fmaxf(mt, __shfl_xor(mt, 16, 64));
            mt = fmaxf(mt, __shfl_xor(mt, 32, 64));
            const float mn = fmaxf(m_, mt);
            const float fac = expf(m_ - mn);
            m_ = mn;
            float rs = 0.f;
            #pragma unroll
            for (int nb = 0; nb < 4; ++nb)
                #pragma unroll
                for (int i = 0; i < 4; ++i) {
                    float pp = expf(sa[nb][i] - mn);
                    sa[nb][i] = pp; rs += pp;
                }
            rs += __shfl_xor(rs, 16, 64);
            rs += __shfl_xor(rs, 32, 64);
            l_ = l_ * fac + rs;
            #pragma unroll
            for (int nd = 0; nd < 4; ++nd) o[nd] *= fac;

            #pragma unroll
            for (int nb = 0; nb < 4; ++nb) {
                u16 fourv[4];
                #pragma unroll
                for (int i = 0; i < 4; ++i) fourv[i] = f2b(sa[nb][i]);
                const int kvb = nb * 16 + li4;
                const int addr = lrow * 64 + (((kvb >> 3) ^ (lrow & 7)) * 8) + (kvb & 7);
                *(short4_t*)(ps + addr) = *(const short4_t*)fourv;
            }
            short8 pa[2];
            pa[0] = *(const short8*)(ps + lrow * 64 + ((ks4 ^ (lrow & 7)) * 8));
            pa[1] = *(const short8*)(ps + lrow * 64 + (((4 + ks4) ^ (lrow & 7)) * 8));
            #pragma unroll
            for (int nd = 0; nd < 4; ++nd)
                #pragma unroll
                for (int kd = 0; kd < 2; ++kd) {
                    const int row = nd * 16 + lrow;
                    short8 vb = *(const short8*)(Vd[p] + row * 64 + (((kd * 4 + ks4) ^ (row & 7)) * 8));
                    o[nd] = __builtin_amdgcn_mfma_f32_16x16x32_bf16(vb, pa[kd], o[nd], 0, 0, 0);
                }
            __syncthreads();
        }

        const float inv = 1.f / l_;
        const long tok = (long)b * NS + qt * 64 + wv * 16 + lrow;
        #pragma unroll
        for (int nd = 0; nd < 4; ++nd) {
            f32x4 v = o[nd] * inv;
            *(f32x4*)(delta + tok * DMODEL + h * 64 + nd * 16 + li4) = v;
        }
    }
}

// ---------------------------------------------------------------------------
extern "C" void kernel_launch(void* const* d_in, const int* in_sizes, int n_in,
                              void* d_out, int out_size, void* d_ws, size_t ws_size,
                              hipStream_t stream) {
    const int*   toks  = (const int*)d_in[0];
    const float* emb   = (const float*)d_in[1];
    const float* Wq    = (const float*)d_in[2];
    const float* Wk    = (const float*)d_in[3];
    const float* Wv    = (const float*)d_in[4];
    const float* W1    = (const float*)d_in[5];
    const float* W2    = (const float*)d_in[6];
    const float* ln1g  = (const float*)d_in[7];
    const float* ln1b  = (const float*)d_in[8];
    const float* ln2g  = (const float*)d_in[9];
    const float* ln2b  = (const float*)d_in[10];
    const float* Wout  = (const float*)d_in[11];
    const float* bout  = (const float*)d_in[12];

    char* p = (char*)d_ws;
    auto alloc = [&](size_t bytes) { void* r = (void*)p; p += (bytes + 255) & ~(size_t)255; return r; };
    const size_t PSZ = (size_t)MTOK * 1024;
    u16*   Wqkv_t = (u16*)alloc((size_t)NLAYER * 3072 * 1024 * 2);
    u16*   W1t    = (u16*)alloc((size_t)NLAYER * 4096 * 1024 * 2);
    u16*   W2t    = (u16*)alloc((size_t)NLAYER * 1024 * 4096 * 2);
    u16*   Woutt  = (u16*)alloc((size_t)NVOCAB * 1024 * 2);
    float* x      = (float*)alloc((size_t)MTOK * 1024 * 4);
    u16*   xb     = (u16*)alloc((size_t)MTOK * 1024 * 2);
    u16*   qkbuf  = (u16*)alloc((size_t)MTOK * 2048 * 2);
    u16*   vTbuf  = (u16*)alloc((size_t)1024 * MTOK * 2);
    u16*   hbuf   = (u16*)alloc((size_t)MTOK * 4096 * 2);
    float* dbuf   = (float*)alloc(PSZ * 2 * 4);

    float* hbufF = (float*)hbuf;

    transpose_qkv<<<dim3(2, 32, 96), dim3(32, 8), 0, stream>>>(Wq, Wqkv_t, 0);
    transpose_qkv<<<dim3(2, 32, 96), dim3(32, 8), 0, stream>>>(Wk, Wqkv_t, 1);
    transpose_qkv<<<dim3(2, 32, 96), dim3(32, 8), 0, stream>>>(Wv, Wqkv_t, 2);
    trans64<<<dim3(64, 16, 6), 256, 0, stream>>>(W1, W1t, 1024, 4096, 1024l * 4096, 4096l * 1024);
    trans64<<<dim3(16, 64, 6), 256, 0, stream>>>(W2, W2t, 4096, 1024, 4096l * 1024, 1024l * 4096);
    trans64<<<dim3(500, 16, 1), 256, 0, stream>>>(Wout, Woutt, 1024, NVOCAB, 0, 0);

    embed_pe<<<MTOK, 256, 0, stream>>>(toks, emb, x, xb);

    for (int l = 0; l < NLAYER; ++l) {
        const u16* Wl = Wqkv_t + (size_t)l * 3072 * 1024;
        gemm_qkv<<<dim3(384), 256, 0, stream>>>(xb, Wl, qkbuf, vTbuf);
        attn_flash4<<<dim3(8, NH, NB), 256, 0, stream>>>(qkbuf, vTbuf, hbufF);
        ln_residual<1><<<MTOK, 256, 0, stream>>>(x, hbufF, 0,
            ln1g + l * 1024, ln1b + l * 1024, x, xb);
        gemm_pipe<128, 2><<<dim3(16 * 32), 256, 0, stream>>>(
            xb, W1t + (size_t)l * 4096 * 1024, hbuf, nullptr, MTOK, 4096, 1024, 1024, 1024, 0);
        gemm_pipe<128, 0><<<dim3(16 * 8, 2), 256, 0, stream>>>(
            hbuf, W2t + (size_t)l * 1024 * 4096, dbuf, nullptr, MTOK, 1024, 2048, 4096, 4096, PSZ);
        ln_residual<2><<<MTOK, 256, 0, stream>>>(x, dbuf, PSZ,
            ln2g + l * 1024, ln2b + l * 1024, x, xb);
    }

    gemm_voc<<<dim3(16 * 125), 256, 0, stream>>>(
        xb, Woutt, (float*)d_out, bout, MTOK, NVOCAB, 1024);
}

// Round 9
// 1106.283 us; speedup vs baseline: 1.0936x; 1.0076x over previous
//
#include <hip/hip_runtime.h>

typedef unsigned short u16;
typedef __attribute__((ext_vector_type(8))) short short8;
typedef __attribute__((ext_vector_type(4))) short short4_t;
typedef __attribute__((ext_vector_type(4))) float f32x4;

#define NLAYER 6
#define NH 16
#define DMODEL 1024
#define DHEAD 64
#define NVOCAB 32000
#define NB 2
#define NS 1024
#define NDFF 4096
#define MTOK (NB*NS)   // 2048

__device__ __forceinline__ u16 f2b(float f) {
    union { float f; unsigned u; } x; x.f = f;
    unsigned r = x.u + 0x7fffu + ((x.u >> 16) & 1u);
    return (u16)(r >> 16);
}

#define GLL16(gp, lp) __builtin_amdgcn_global_load_lds( \
    (const __attribute__((address_space(1))) void*)(gp), \
    (__attribute__((address_space(3))) void*)(lp), 16, 0, 0)

// ---------------------------------------------------------------------------
__global__ __launch_bounds__(256) void trans64(
    const float* __restrict__ src, u16* __restrict__ dst,
    int R, int C, long sStride, long dStride)
{
    __shared__ float sh[64][65];
    const int c0 = blockIdx.x * 64, r0 = blockIdx.y * 64;
    const float* s = src + (long)blockIdx.z * sStride;
    u16* d = dst + (long)blockIdx.z * dStride;
    const int tid = threadIdx.x;
    const int lr = tid >> 4, lc = (tid & 15) * 4;
    #pragma unroll
    for (int q = 0; q < 4; ++q) {
        const float4 v = *(const float4*)(s + (long)(r0 + q * 16 + lr) * C + c0 + lc);
        sh[q * 16 + lr][lc + 0] = v.x;
        sh[q * 16 + lr][lc + 1] = v.y;
        sh[q * 16 + lr][lc + 2] = v.z;
        sh[q * 16 + lr][lc + 3] = v.w;
    }
    __syncthreads();
    #pragma unroll
    for (int k = 0; k < 2; ++k) {
        const int t = tid + 256 * k;
        const int col = t >> 3, rch = (t & 7) * 8;
        u16 tmp[8];
        #pragma unroll
        for (int j = 0; j < 8; ++j) tmp[j] = f2b(sh[rch + j][col]);
        *(short8*)(d + (long)(c0 + col) * R + r0 + rch) = *(const short8*)tmp;
    }
}

__global__ void transpose_qkv(const float* __restrict__ src, u16* __restrict__ dst, int sel)
{
    __shared__ float t[32][33];
    const int bi = blockIdx.z, l = bi >> 4, h = bi & 15;
    const float* s = src + (long)bi * (DMODEL * DHEAD);
    u16* d = dst + (long)l * 3072 * DMODEL + (long)(sel * 1024 + h * 64) * DMODEL;
    const int c0 = blockIdx.x * 32, r0 = blockIdx.y * 32;
    const int tx = threadIdx.x, ty = threadIdx.y;
    #pragma unroll
    for (int j = 0; j < 32; j += 8)
        t[ty + j][tx] = s[(long)(r0 + ty + j) * DHEAD + c0 + tx];
    __syncthreads();
    #pragma unroll
    for (int j = 0; j < 32; j += 8)
        d[(long)(c0 + ty + j) * DMODEL + r0 + tx] = f2b(t[tx][ty + j]);
}

// ---------------------------------------------------------------------------
__global__ void embed_pe(const int* __restrict__ toks, const float* __restrict__ emb,
                         float* __restrict__ x, u16* __restrict__ xb)
{
    const int row = blockIdx.x;
    const int s = row & (NS - 1);
    const long erow = (long)toks[row] * DMODEL;
    const long base = (long)row * DMODEL;
    #pragma unroll
    for (int j = 0; j < 4; ++j) {
        int d = threadIdx.x + j * 256;
        float ang = (float)s * exp2f(-(float)d * (9.965784284662087f / 1024.f));
        float pe = (d & 1) ? cosf(ang) : sinf(ang);
        float v = emb[erow + d] + pe;
        x[base + d] = v;
        xb[base + d] = f2b(v);
    }
}

// ---------------------------------------------------------------------------
template<int ND>
__global__ __launch_bounds__(256) void ln_residual(
    const float* __restrict__ xin, const float* __restrict__ delta, size_t pstride,
    const float* __restrict__ g, const float* __restrict__ bb,
    float* __restrict__ xout, u16* __restrict__ xbout)
{
    __shared__ float red[8];
    const long base = (long)blockIdx.x * DMODEL;
    const int d = threadIdx.x * 4;
    f32x4 v = *(const f32x4*)(xin + base + d);
    #pragma unroll
    for (int y = 0; y < ND; ++y)
        v += *(const f32x4*)(delta + base + (size_t)y * pstride + d);
    float sum = v[0] + v[1] + v[2] + v[3];
    float sq  = v[0]*v[0] + v[1]*v[1] + v[2]*v[2] + v[3]*v[3];
    #pragma unroll
    for (int off = 1; off < 64; off <<= 1) {
        sum += __shfl_xor(sum, off, 64);
        sq  += __shfl_xor(sq,  off, 64);
    }
    const int wv = threadIdx.x >> 6, lane = threadIdx.x & 63;
    if (lane == 0) { red[wv] = sum; red[4 + wv] = sq; }
    __syncthreads();
    float ts = red[0] + red[1] + red[2] + red[3];
    float tq = red[4] + red[5] + red[6] + red[7];
    float mu = ts * (1.f / DMODEL);
    float var = tq * (1.f / DMODEL) - mu * mu;
    float rstd = rsqrtf(var + 1e-5f);
    const f32x4 gg = *(const f32x4*)(g + d);
    const f32x4 bv = *(const f32x4*)(bb + d);
    f32x4 yv = (v - mu) * rstd * gg + bv;
    *(f32x4*)(xout + base + d) = yv;
    u16 fourv[4];
    #pragma unroll
    for (int i = 0; i < 4; ++i) fourv[i] = f2b(yv[i]);
    *(short4_t*)(xbout + base + d) = *(const short4_t*)fourv;
}

// ---------------------------------------------------------------------------
// r5-proven pipelined GEMM body (16x16x32, BK=32, 4 LDS slots, vmcnt(8),
// XOR swizzle, XCD swizzle). Shared arrays passed in (so kernels can merge).
template<int BM, int EPI>
__device__ __forceinline__ void gemm_body(
    const u16* __restrict__ A, const u16* __restrict__ Bt,
    void* __restrict__ Cout, const float* __restrict__ bias,
    int M, int N, int K, int lda, int ldb, size_t zstride,
    int id, int nwg, int zidx, u16* Asp, u16* Bsp)
{
    constexpr int WAVES = BM / 32;
    constexpr int WC = WAVES / 2;
    constexpr int MR = BM / 32;
    constexpr int TILE = BM * 32;

    const int nmb = M / BM;
    const int q = nwg >> 3, r = nwg & 7, xcd = id & 7, loc = id >> 3;
    const int swz = (xcd < r ? xcd * (q + 1) : r * (q + 1) + (xcd - r) * q) + loc;
    const int m0 = (swz % nmb) * BM, n0 = (swz / nmb) * BM;
    const int koff = zidx * K;

    const int tid = threadIdx.x, wv = tid >> 6, lane = tid & 63;
    const int wr = wv / WC, wc = wv % WC;
    const int lrow = lane & 15, ks = lane >> 4;

    const u16* gsrc[4];
    int ldso[2];
    {
        const int l4 = lane >> 2, s = lane & 3;
        #pragma unroll
        for (int j = 0; j < 2; ++j) {
            const int row = j * (WAVES * 16) + wv * 16 + l4;
            const int x = (row >> 1) & 3;
            gsrc[j]     = A  + (size_t)(m0 + row) * lda + koff + (size_t)((s ^ x) * 8);
            gsrc[2 + j] = Bt + (size_t)(n0 + row) * ldb + koff + (size_t)((s ^ x) * 8);
            ldso[j] = (j * (WAVES * 16) + wv * 16) * 32;
        }
    }
    int aoff[MR], boff[4];
    #pragma unroll
    for (int m = 0; m < MR; ++m) {
        const int row = wr * (BM / 2) + m * 16 + lrow;
        aoff[m] = row * 32 + ((ks ^ ((row >> 1) & 3)) * 8);
    }
    #pragma unroll
    for (int n = 0; n < 4; ++n) {
        const int row = wc * 64 + n * 16 + lrow;
        boff[n] = row * 32 + ((ks ^ ((row >> 1) & 3)) * 8);
    }

    const int NT = K / 32;
    auto ISSUE = [&](int t) {
        const int b = t & 3;
        const size_t ko = (size_t)t * 32;
        #pragma unroll
        for (int j = 0; j < 2; ++j) {
            GLL16(gsrc[j] + ko,     Asp + b * TILE + ldso[j]);
            GLL16(gsrc[2 + j] + ko, Bsp + b * TILE + ldso[j]);
        }
    };

    f32x4 acc[MR][4] = {};
    ISSUE(0); ISSUE(1); ISSUE(2);

    for (int t = 0; t < NT; ++t) {
        if (t < NT - 2)       { asm volatile("s_waitcnt vmcnt(8)" ::: "memory"); }
        else if (t == NT - 2) { asm volatile("s_waitcnt vmcnt(4)" ::: "memory"); }
        else                  { asm volatile("s_waitcnt vmcnt(0)" ::: "memory"); }
        __builtin_amdgcn_sched_barrier(0);
        __builtin_amdgcn_s_barrier();
        __builtin_amdgcn_sched_barrier(0);

        const int b = t & 3;
        short8 af[MR], bf[4];
        #pragma unroll
        for (int m = 0; m < MR; ++m) af[m] = *(const short8*)(Asp + b * TILE + aoff[m]);
        #pragma unroll
        for (int n = 0; n < 4; ++n)  bf[n] = *(const short8*)(Bsp + b * TILE + boff[n]);
        if (t + 3 < NT) ISSUE(t + 3);
        __builtin_amdgcn_s_setprio(1);
        #pragma unroll
        for (int m = 0; m < MR; ++m)
            #pragma unroll
            for (int n = 0; n < 4; ++n)
                acc[m][n] = __builtin_amdgcn_mfma_f32_16x16x32_bf16(af[m], bf[n], acc[m][n], 0, 0, 0);
        __builtin_amdgcn_s_setprio(0);
    }

    if (EPI == 0 || EPI == 3) {
        __syncthreads();
        float* patch = (float*)((WAVES == 8 && (wv & 4)) ? (void*)Bsp : (void*)Asp)
                       + (wv & 3) * (16 * 68);
        const int cc0 = n0 + wc * 64;
        f32x4 bvv = {};
        if (EPI == 3) bvv = *(const f32x4*)(bias + cc0 + (lane & 15) * 4);
        float* C = (float*)Cout + (EPI == 0 ? (size_t)zidx * zstride : (size_t)0);
        #pragma unroll
        for (int m = 0; m < MR; ++m) {
            #pragma unroll
            for (int n = 0; n < 4; ++n)
                #pragma unroll
                for (int i = 0; i < 4; ++i)
                    patch[(ks * 4 + i) * 68 + n * 16 + lrow] = acc[m][n][i];
            #pragma unroll
            for (int i2 = 0; i2 < 4; ++i2) {
                const int prow = i2 * 4 + ks;
                f32x4 v = *(const f32x4*)(patch + prow * 68 + (lane & 15) * 4);
                if (EPI == 3) v += bvv;
                const int rr = m0 + wr * (BM / 2) + m * 16 + prow;
                *(f32x4*)(C + (size_t)rr * N + cc0 + (lane & 15) * 4) = v;
            }
        }
    } else {
        u16* C = (u16*)Cout;
        #pragma unroll
        for (int m = 0; m < MR; ++m) {
            const int rr = m0 + wr * (BM / 2) + m * 16 + ks * 4;
            #pragma unroll
            for (int n = 0; n < 4; ++n) {
                const int cc = n0 + wc * 64 + n * 16 + lrow;
                #pragma unroll
                for (int i = 0; i < 4; ++i) {
                    float vv = acc[m][n][i];
                    if (EPI == 2) vv = fmaxf(vv, 0.f);
                    C[(size_t)(rr + i) * N + cc] = f2b(vv);
                }
            }
        }
    }
}

template<int BM, int EPI>
__global__ __launch_bounds__(BM*2, 2) void gemm_pipe(
    const u16* __restrict__ A, const u16* __restrict__ Bt,
    void* __restrict__ Cout, const float* __restrict__ bias,
    int M, int N, int K, int lda, int ldb, size_t zstride)
{
    __shared__ __align__(16) u16 As[4][BM * 32];
    __shared__ __align__(16) u16 Bs[4][BM * 32];
    gemm_body<BM, EPI>(A, Bt, Cout, bias, M, N, K, lda, ldb, zstride,
                       blockIdx.x, gridDim.x, blockIdx.y, &As[0][0], &Bs[0][0]);
}

// Merged per-layer projection: blocks 0..255 = qk GEMM, 256..383 = vT GEMM
__global__ __launch_bounds__(256, 2) void gemm_qkv(
    const u16* __restrict__ xb, const u16* __restrict__ Wl,
    u16* __restrict__ qkbuf, u16* __restrict__ vTbuf)
{
    __shared__ __align__(16) u16 As[4][128 * 32];
    __shared__ __align__(16) u16 Bs[4][128 * 32];
    if (blockIdx.x < 256)
        gemm_body<128, 1>(xb, Wl, qkbuf, nullptr, MTOK, 2048, 1024, 1024, 1024, 0,
                          blockIdx.x, 256, 0, &As[0][0], &Bs[0][0]);
    else
        gemm_body<128, 1>(Wl + (size_t)2048 * 1024, xb, vTbuf, nullptr, 1024, MTOK, 1024,
                          1024, 1024, 0, blockIdx.x - 256, 128, 0, &As[0][0], &Bs[0][0]);
}

// ---------------------------------------------------------------------------
// Flash attention v4 (r5-exact)
__global__ __launch_bounds__(256, 2) void attn_flash4(
    const u16* __restrict__ qk, const u16* __restrict__ vT, float* __restrict__ delta)
{
    __shared__ __align__(16) u16 Qs[64 * 64];
    __shared__ __align__(16) u16 Kd[2][64 * 64];
    __shared__ __align__(16) u16 Vd[2][64 * 64];
    __shared__ __align__(16) u16 Ps[4][16 * 64];

    const int pair = blockIdx.x, h = blockIdx.y, b = blockIdx.z;
    const int tid = threadIdx.x, wv = tid >> 6, lane = tid & 63;
    const int lrow = lane & 15, ks4 = lane >> 4, li4 = ks4 * 4;
    const long baseQK = (long)b * NS * 2048;
    const u16* vbase = vT + (long)h * 64 * 2048 + b * NS;
    u16* ps = &Ps[wv][0];

    for (int rep = 0; rep < 2; ++rep) {
        const int qt = rep ? 15 - pair : pair;
        __syncthreads();

        #pragma unroll
        for (int i = 0; i < 2; ++i) {
            const int c = (wv * 2 + i) * 64 + lane;
            const int row = c >> 3, u = (c & 7) ^ (row & 7);
            GLL16(qk + baseQK + (long)(qt * 64 + row) * 2048 + h * 64 + u * 8, Qs + c * 8);
            GLL16(qk + baseQK + (long)row * 2048 + 1024 + h * 64 + u * 8, Kd[0] + c * 8);
            GLL16(vbase + (long)row * 2048 + u * 8, Vd[0] + c * 8);
        }
        __syncthreads();

        short8 aq[2];
        {
            const int row = wv * 16 + lrow;
            aq[0] = *(const short8*)(Qs + row * 64 + ((ks4 ^ (row & 7)) * 8));
            aq[1] = *(const short8*)(Qs + row * 64 + (((4 + ks4) ^ (row & 7)) * 8));
        }

        f32x4 o[4] = {};
        float m_ = -__builtin_inff(), l_ = 0.f;

        for (int t = 0; t <= qt; ++t) {
            const int p = t & 1;
            if (t < qt) {
                #pragma unroll
                for (int i = 0; i < 2; ++i) {
                    const int c = (wv * 2 + i) * 64 + lane;
                    const int row = c >> 3, u = (c & 7) ^ (row & 7);
                    GLL16(qk + baseQK + (long)((t + 1) * 64 + row) * 2048 + 1024 + h * 64 + u * 8, Kd[p ^ 1] + c * 8);
                    GLL16(vbase + (long)row * 2048 + (t + 1) * 64 + u * 8, Vd[p ^ 1] + c * 8);
                }
            }
            f32x4 sa[4];
            #pragma unroll
            for (int nb = 0; nb < 4; ++nb) {
                f32x4 z = {};
                #pragma unroll
                for (int kd = 0; kd < 2; ++kd) {
                    const int row = nb * 16 + lrow;
                    short8 bk = *(const short8*)(Kd[p] + row * 64 + (((kd * 4 + ks4) ^ (row & 7)) * 8));
                    z = __builtin_amdgcn_mfma_f32_16x16x32_bf16(bk, aq[kd], z, 0, 0, 0);
                }
                sa[nb] = z;
            }
            const int qg = qt * 64 + wv * 16 + lrow;
            #pragma unroll
            for (int nb = 0; nb < 4; ++nb)
                #pragma unroll
                for (int i = 0; i < 4; ++i) {
                    float sc = sa[nb][i] * 0.125f;
                    if (t == qt && (t * 64 + nb * 16 + li4 + i) > qg) sc = -__builtin_inff();
                    sa[nb][i] = sc;
                }
            float mt = sa[0][0];
            #pragma unroll
            for (int nb = 0; nb < 4; ++nb)
                #pragma unroll
                for (int i = 0; i < 4; ++i) mt = fmaxf(mt, sa[nb][i]);
            mt = fmaxf(mt, __shfl_xor(mt, 16, 64));
            mt = fmaxf(mt, __shfl_xor(mt, 32, 64));
            const float mn = fmaxf(m_, mt);
            const float fac = expf(m_ - mn);
            m_ = mn;
            float rs = 0.f;
            #pragma unroll
            for (int nb = 0; nb < 4; ++nb)
                #pragma unroll
                for (int i = 0; i < 4; ++i) {
                    float pp = expf(sa[nb][i] - mn);
                    sa[nb][i] = pp; rs += pp;
                }
            rs += __shfl_xor(rs, 16, 64);
            rs += __shfl_xor(rs, 32, 64);
            l_ = l_ * fac + rs;
            #pragma unroll
            for (int nd = 0; nd < 4; ++nd) o[nd] *= fac;

            #pragma unroll
            for (int nb = 0; nb < 4; ++nb) {
                u16 fourv[4];
                #pragma unroll
                for (int i = 0; i < 4; ++i) fourv[i] = f2b(sa[nb][i]);
                const int kvb = nb * 16 + li4;
                const int addr = lrow * 64 + (((kvb >> 3) ^ (lrow & 7)) * 8) + (kvb & 7);
                *(short4_t*)(ps + addr) = *(const short4_t*)fourv;
            }
            short8 pa[2];
            pa[0] = *(const short8*)(ps + lrow * 64 + ((ks4 ^ (lrow & 7)) * 8));
            pa[1] = *(const short8*)(ps + lrow * 64 + (((4 + ks4) ^ (lrow & 7)) * 8));
            #pragma unroll
            for (int nd = 0; nd < 4; ++nd)
                #pragma unroll
                for (int kd = 0; kd < 2; ++kd) {
                    const int row = nd * 16 + lrow;
                    short8 vb = *(const short8*)(Vd[p] + row * 64 + (((kd * 4 + ks4) ^ (row & 7)) * 8));
                    o[nd] = __builtin_amdgcn_mfma_f32_16x16x32_bf16(vb, pa[kd], o[nd], 0, 0, 0);
                }
            __syncthreads();
        }

        const float inv = 1.f / l_;
        const long tok = (long)b * NS + qt * 64 + wv * 16 + lrow;
        #pragma unroll
        for (int nd = 0; nd < 4; ++nd) {
            f32x4 v = o[nd] * inv;
            *(f32x4*)(delta + tok * DMODEL + h * 64 + nd * 16 + li4) = v;
        }
    }
}

// ---------------------------------------------------------------------------
extern "C" void kernel_launch(void* const* d_in, const int* in_sizes, int n_in,
                              void* d_out, int out_size, void* d_ws, size_t ws_size,
                              hipStream_t stream) {
    const int*   toks  = (const int*)d_in[0];
    const float* emb   = (const float*)d_in[1];
    const float* Wq    = (const float*)d_in[2];
    const float* Wk    = (const float*)d_in[3];
    const float* Wv    = (const float*)d_in[4];
    const float* W1    = (const float*)d_in[5];
    const float* W2    = (const float*)d_in[6];
    const float* ln1g  = (const float*)d_in[7];
    const float* ln1b  = (const float*)d_in[8];
    const float* ln2g  = (const float*)d_in[9];
    const float* ln2b  = (const float*)d_in[10];
    const float* Wout  = (const float*)d_in[11];
    const float* bout  = (const float*)d_in[12];

    char* p = (char*)d_ws;
    auto alloc = [&](size_t bytes) { void* r = (void*)p; p += (bytes + 255) & ~(size_t)255; return r; };
    const size_t PSZ = (size_t)MTOK * 1024;
    u16*   Wqkv_t = (u16*)alloc((size_t)NLAYER * 3072 * 1024 * 2);
    u16*   W1t    = (u16*)alloc((size_t)NLAYER * 4096 * 1024 * 2);
    u16*   W2t    = (u16*)alloc((size_t)NLAYER * 1024 * 4096 * 2);
    u16*   Woutt  = (u16*)alloc((size_t)NVOCAB * 1024 * 2);
    float* x      = (float*)alloc((size_t)MTOK * 1024 * 4);
    u16*   xb     = (u16*)alloc((size_t)MTOK * 1024 * 2);
    u16*   qkbuf  = (u16*)alloc((size_t)MTOK * 2048 * 2);
    u16*   vTbuf  = (u16*)alloc((size_t)1024 * MTOK * 2);
    u16*   hbuf   = (u16*)alloc((size_t)MTOK * 4096 * 2);
    float* dbuf   = (float*)alloc(PSZ * 2 * 4);

    float* hbufF = (float*)hbuf;

    transpose_qkv<<<dim3(2, 32, 96), dim3(32, 8), 0, stream>>>(Wq, Wqkv_t, 0);
    transpose_qkv<<<dim3(2, 32, 96), dim3(32, 8), 0, stream>>>(Wk, Wqkv_t, 1);
    transpose_qkv<<<dim3(2, 32, 96), dim3(32, 8), 0, stream>>>(Wv, Wqkv_t, 2);
    trans64<<<dim3(64, 16, 6), 256, 0, stream>>>(W1, W1t, 1024, 4096, 1024l * 4096, 4096l * 1024);
    trans64<<<dim3(16, 64, 6), 256, 0, stream>>>(W2, W2t, 4096, 1024, 4096l * 1024, 1024l * 4096);
    trans64<<<dim3(500, 16, 1), 256, 0, stream>>>(Wout, Woutt, 1024, NVOCAB, 0, 0);

    embed_pe<<<MTOK, 256, 0, stream>>>(toks, emb, x, xb);

    for (int l = 0; l < NLAYER; ++l) {
        const u16* Wl = Wqkv_t + (size_t)l * 3072 * 1024;
        gemm_qkv<<<dim3(384), 256, 0, stream>>>(xb, Wl, qkbuf, vTbuf);
        attn_flash4<<<dim3(8, NH, NB), 256, 0, stream>>>(qkbuf, vTbuf, hbufF);
        ln_residual<1><<<MTOK, 256, 0, stream>>>(x, hbufF, 0,
            ln1g + l * 1024, ln1b + l * 1024, x, xb);
        gemm_pipe<128, 2><<<dim3(16 * 32), 256, 0, stream>>>(
            xb, W1t + (size_t)l * 4096 * 1024, hbuf, nullptr, MTOK, 4096, 1024, 1024, 1024, 0);
        gemm_pipe<128, 0><<<dim3(16 * 8, 2), 256, 0, stream>>>(
            hbuf, W2t + (size_t)l * 1024 * 4096, dbuf, nullptr, MTOK, 1024, 2048, 4096, 4096, PSZ);
        ln_residual<2><<<MTOK, 256, 0, stream>>>(x, dbuf, PSZ,
            ln2g + l * 1024, ln2b + l * 1024, x, xb);
    }

    gemm_pipe<256, 3><<<dim3(8 * 125), 512, 0, stream>>>(
        xb, Woutt, (float*)d_out, bout, MTOK, NVOCAB, 1024, 1024, 1024, 0);
}